// Round 5
// baseline (397.947 us; speedup 1.0000x reference)
//
#include <hip/hip_runtime.h>

typedef float f32x4 __attribute__((ext_vector_type(4)));
typedef short s16x8 __attribute__((ext_vector_type(8)));
typedef unsigned short u16;

__device__ __forceinline__ u16 f2bf(float f) {
    union { float f; unsigned u; } v; v.f = f;
    return (u16)((v.u + 0x7fffu + ((v.u >> 16) & 1u)) >> 16);
}
__device__ __forceinline__ float bf2f(u16 h) {
    union { unsigned u; float f; } v; v.u = ((unsigned)h) << 16;
    return v.f;
}
__device__ __forceinline__ float fast_exp2(float x) {
#if __has_builtin(__builtin_amdgcn_exp2f)
    return __builtin_amdgcn_exp2f(x);
#else
    return exp2f(x);
#endif
}

// async global->LDS, 16B/lane; LDS dest = wave-uniform base + lane*16 [m97/m104]
__device__ __forceinline__ void gload_lds16(const void* g, void* l) {
    __builtin_amdgcn_global_load_lds((__attribute__((address_space(1))) void*)g,
                                     (__attribute__((address_space(3))) void*)l, 16, 0, 0);
}

// Mega convert: x (1048576 units) -> xb, then wq|wk|wv -> wqkvb contiguous. 1 unit = 8 elems.
__global__ __launch_bounds__(256) void cvt_all(const float* __restrict__ x,  const float* __restrict__ wq,
                                               const float* __restrict__ wk, const float* __restrict__ wv,
                                               u16* __restrict__ xb, u16* __restrict__ wqkvb) {
    int u = blockIdx.x * 256 + threadIdx.x;
    const float* src;
    u16* dst;
    if (u < 1048576) { src = x + (size_t)u * 8; dst = xb + (size_t)u * 8; }
    else {
        int w = u - 1048576;
        dst = wqkvb + (size_t)w * 8;
        if (w < 524288)      src = wq + (size_t)w * 8;
        else if (w < 655360) src = wk + (size_t)(w - 524288) * 8;
        else                 src = wv + (size_t)(w - 655360) * 8;
    }
    const float4* p = (const float4*)src;
    float4 a = p[0], b = p[1];
    s16x8 o;
    o[0] = f2bf(a.x); o[1] = f2bf(a.y); o[2] = f2bf(a.z); o[3] = f2bf(a.w);
    o[4] = f2bf(b.x); o[5] = f2bf(b.y); o[6] = f2bf(b.z); o[7] = f2bf(b.w);
    *(s16x8*)dst = o;
}

__global__ __launch_bounds__(256) void cvt_kernel(const float* __restrict__ in,
                                                  u16* __restrict__ out, int n8) {
    int i = blockIdx.x * 256 + threadIdx.x;
    if (i >= n8) return;
    const float4* p = (const float4*)(in + (size_t)i * 8);
    float4 a = p[0], b = p[1];
    s16x8 o;
    o[0] = f2bf(a.x); o[1] = f2bf(a.y); o[2] = f2bf(a.z); o[3] = f2bf(a.w);
    o[4] = f2bf(b.x); o[5] = f2bf(b.y); o[6] = f2bf(b.z); o[7] = f2bf(b.w);
    *(s16x8*)(out + (size_t)i * 8) = o;
}

// C = A[M,K] @ B[N,K]^T, bf16 in. 128x128 tile, BK=64, global_load_lds staging,
// XOR-swizzled LDS. OUT=1: fp32 C[M,N]. OUT=4: fused qkv routing.
template<int OUT>
__global__ __launch_bounds__(256) void gemm128(const u16* __restrict__ A, const u16* __restrict__ B,
                                               void* __restrict__ C, void* __restrict__ Ck,
                                               void* __restrict__ Cv, int M, int N, int K) {
    __shared__ __align__(16) u16 Ald[128 * 64];
    __shared__ __align__(16) u16 Bld[128 * 64];
    const int t = threadIdx.x, wid = t >> 6, lane = t & 63;
    const int m0 = blockIdx.y * 128, n0 = blockIdx.x * 128;
    const int ml = lane & 15, quad = lane >> 4, m7 = ml & 7;
    const int wm = (wid & 1) * 64, wn = (wid >> 1) * 64;
    const int sr = lane >> 3, sc = lane & 7;

    f32x4 acc[4][4] = {};

    for (int k0 = 0; k0 < K; k0 += 64) {
        if (k0) __syncthreads();
        #pragma unroll
        for (int i = 0; i < 4; ++i) {
            int seg = wid * 4 + i;
            int r = seg * 8 + sr;
            int c = (sc ^ (r & 7)) * 8;
            gload_lds16(A + (size_t)(m0 + r) * K + k0 + c, &Ald[seg * 512]);
            gload_lds16(B + (size_t)(n0 + r) * K + k0 + c, &Bld[seg * 512]);
        }
        __syncthreads();
        #pragma unroll
        for (int kk = 0; kk < 64; kk += 32) {
            s16x8 af[4], bf[4];
            #pragma unroll
            for (int mi = 0; mi < 4; ++mi)
                af[mi] = *(const s16x8*)&Ald[(wm + mi * 16 + ml) * 64 + (((kk >> 3) + quad) ^ m7) * 8];
            #pragma unroll
            for (int ni = 0; ni < 4; ++ni)
                bf[ni] = *(const s16x8*)&Bld[(wn + ni * 16 + ml) * 64 + (((kk >> 3) + quad) ^ m7) * 8];
            #pragma unroll
            for (int mi = 0; mi < 4; ++mi)
                #pragma unroll
                for (int ni = 0; ni < 4; ++ni)
                    acc[mi][ni] = __builtin_amdgcn_mfma_f32_16x16x32_bf16(af[mi], bf[ni], acc[mi][ni], 0, 0, 0);
        }
    }
    // C/D layout: col=lane&15, row=quad*4+reg [m89/m91]
    #pragma unroll
    for (int mi = 0; mi < 4; ++mi)
        #pragma unroll
        for (int ni = 0; ni < 4; ++ni) {
            int gmb = m0 + wm + mi * 16 + quad * 4;
            int gn  = n0 + wn + ni * 16 + ml;
            if constexpr (OUT == 4) {
                if (n0 < 2048) {
                    #pragma unroll
                    for (int r = 0; r < 4; ++r)
                        ((u16*)C)[(size_t)(gmb + r) * 2048 + gn] = f2bf(acc[mi][ni][r]);
                } else if (n0 < 2560) {
                    #pragma unroll
                    for (int r = 0; r < 4; ++r)
                        ((u16*)Ck)[(size_t)(gmb + r) * 512 + (gn - 2048)] = f2bf(acc[mi][ni][r]);
                } else {
                    ushort4 v;
                    v.x = f2bf(acc[mi][ni][0]); v.y = f2bf(acc[mi][ni][1]);
                    v.z = f2bf(acc[mi][ni][2]); v.w = f2bf(acc[mi][ni][3]);
                    *(ushort4*)((u16*)Cv + (size_t)(gn - 2560) * M + gmb) = v;
                }
            } else {
                #pragma unroll
                for (int r = 0; r < 4; ++r)
                    ((float*)C)[(size_t)(gmb + r) * N + gn] = acc[mi][ni][r];
            }
        }
}

// Fused NeoX RoPE for q (16 heads, scaled by 1/sqrt(128)*log2e) + k (4 heads).
__global__ __launch_bounds__(256) void rope_kernel(u16* __restrict__ qb, u16* __restrict__ kb,
                                                   int nq, int ntot, float sq) {
    int idx = blockIdx.x * 256 + threadIdx.x;
    if (idx >= ntot) return;
    u16* base; int nheads; float scl; int id;
    if (idx < nq) { base = qb; nheads = 16; scl = sq;  id = idx; }
    else          { base = kb; nheads = 4;  scl = 1.f; id = idx - nq; }
    int i = id & 63;
    int rest = id >> 6;
    int hh = rest % nheads;
    int tok = rest / nheads;
    int tpos = tok & 2047;
    u16* row = base + (size_t)tok * nheads * 128 + hh * 128;
    float x1 = bf2f(row[i]);
    float x2 = bf2f(row[i + 64]);
    float inv = expf(-(float)i * 0.14391156731570787f); // 10000^(-i/64)
    float ang = (float)tpos * inv;
    float s, c;
    sincosf(ang, &s, &c);
    row[i]      = f2bf((x1 * c - x2 * s) * scl);
    row[i + 64] = f2bf((x2 * c + x1 * s) * scl);
}

// Flash attention v3: 2-wave blocks (2 heads of a kv group), balanced q-tile pairs,
// s-chunks of 32 with DOUBLE-BUFFERED K/V staging (1 barrier/iter, prefetch issued
// after the barrier so loads fly during compute). No-max log2-domain softmax,
// l via ones-column MFMA, pair-shared kf/vf fragments (each feeds 2 MFMAs).
// LDS = 2*8K (K) + 2*8K (V) + 4K (P) = 36KB -> 4 blocks/CU; grid 1024 -> 16 waves/CU.
__global__ __launch_bounds__(128, 4) void attn_kernel(const u16* __restrict__ Q, const u16* __restrict__ Kb,
                                                      const u16* __restrict__ Vt, u16* __restrict__ O) {
    __shared__ __align__(16) u16 Klds[2][32 * 128];   // 8KB x2
    __shared__ __align__(16) u16 Vlds[2][128 * 32];   // 8KB x2
    __shared__ __align__(16) u16 Plds[2][2][16 * 32]; // [wave][tile] 1KB, 4KB total
    const int t = threadIdx.x, wslot = t >> 6, lane = t & 63;
    const int qa = blockIdx.x, qbt = 127 - (int)blockIdx.x;
    const int kv = blockIdx.y >> 1, hgrp = blockIdx.y & 1, b = blockIdx.z;
    const int h = kv * 4 + hgrp * 2 + wslot;
    const int ml = lane & 15, quad = lane >> 4, m3 = ml & 3;
    const int t0a = qa * 16, t0b = qbt * 16;

    // Q fragments: A layout m=lane&15, k=quad*8+j [m120]
    s16x8 qfA[4], qfB[4];
    {
        const u16* qpA = Q + ((size_t)(b * 2048 + t0a + ml) * 2048 + h * 128);
        const u16* qpB = Q + ((size_t)(b * 2048 + t0b + ml) * 2048 + h * 128);
        #pragma unroll
        for (int kc = 0; kc < 4; ++kc) {
            qfA[kc] = *(const s16x8*)(qpA + kc * 32 + quad * 8);
            qfB[kc] = *(const s16x8*)(qpB + kc * 32 + quad * 8);
        }
    }

    s16x8 ones;
    #pragma unroll
    for (int j = 0; j < 8; ++j) ones[j] = (short)0x3F80; // bf16 1.0

    f32x4 OA[8] = {}, OB[8] = {};
    f32x4 LA = {}, LB = {};

    const int La = (t0a >> 5) + 1; // s-chunks for tile A
    const int Lb = (t0b >> 5) + 1; // always > La

    // stage s-chunk c into buffer bi (per wave: 4 K segs + 4 V segs, swizzled src)
    auto stage = [&](int bi, int c) {
        const int s0 = c * 32;
        #pragma unroll
        for (int i = 0; i < 4; ++i) {
            int kseg = wslot * 4 + i;                       // 8 segs of 4 rows x 256B
            int krow = kseg * 4 + (lane >> 4);
            int kch  = (lane & 15) ^ (krow & 7);
            gload_lds16(Kb + (size_t)(b * 2048 + s0 + krow) * 512 + kv * 128 + kch * 8,
                        &Klds[bi][kseg * 512]);
            int vseg = wslot * 4 + i;                       // 8 segs of 16 rows x 64B
            int vrow = vseg * 16 + (lane >> 2);
            int vch  = (lane & 3) ^ (vrow & 3);
            gload_lds16(Vt + (size_t)(kv * 128 + vrow) * 4096 + b * 2048 + s0 + vch * 8,
                        &Vlds[bi][vseg * 512]);
        }
    };

    stage(0, 0);

    for (int c = 0; c < Lb; ++c) {
        __syncthreads();                 // buf[c&1] staged; buf[(c+1)&1] free
        if (c + 1 < Lb) stage((c + 1) & 1, c + 1);
        const u16* kl = Klds[c & 1];
        const u16* vl = Vlds[c & 1];
        const int s0 = c * 32;
        const bool actA  = (c < La);
        const bool maskA = (c == La - 1);
        const bool maskB = (c == Lb - 1);

        // QK^T (shared kf)
        f32x4 Sa[2] = {}, Sb[2] = {};
        if (actA) {
            #pragma unroll
            for (int kc = 0; kc < 4; ++kc)
                #pragma unroll
                for (int ti = 0; ti < 2; ++ti) {
                    s16x8 kf = *(const s16x8*)&kl[(ti * 16 + ml) * 128 + (((kc * 4 + quad) ^ (ml & 7)) * 8)];
                    Sb[ti] = __builtin_amdgcn_mfma_f32_16x16x32_bf16(qfB[kc], kf, Sb[ti], 0, 0, 0);
                    Sa[ti] = __builtin_amdgcn_mfma_f32_16x16x32_bf16(qfA[kc], kf, Sa[ti], 0, 0, 0);
                }
        } else {
            #pragma unroll
            for (int kc = 0; kc < 4; ++kc)
                #pragma unroll
                for (int ti = 0; ti < 2; ++ti) {
                    s16x8 kf = *(const s16x8*)&kl[(ti * 16 + ml) * 128 + (((kc * 4 + quad) ^ (ml & 7)) * 8)];
                    Sb[ti] = __builtin_amdgcn_mfma_f32_16x16x32_bf16(qfB[kc], kf, Sb[ti], 0, 0, 0);
                }
        }

        // softmax (no max-shift): p = exp2(s), causal mask only on the diagonal chunk
        auto do_soft = [&](f32x4* S, int t0, int pslot, bool msk) {
            u16* pl = &Plds[wslot][pslot][0];
            #pragma unroll
            for (int r = 0; r < 4; ++r) {
                int row = quad * 4 + r;
                int qr = t0 + row;
                #pragma unroll
                for (int ti = 0; ti < 2; ++ti) {
                    float e = fast_exp2(S[ti][r]);
                    if (msk && (s0 + ti * 16 + ml > qr)) e = 0.f;
                    union { float f; unsigned u; } cv; cv.f = e;
                    pl[row * 32 + (((ti * 2 + (ml >> 3)) ^ (row & 3)) * 8) + (ml & 7)] = (u16)(cv.u >> 16);
                }
            }
        };
        do_soft(Sb, t0b, 1, maskB);
        if (actA) do_soft(Sa, t0a, 0, maskA);
        asm volatile("s_waitcnt lgkmcnt(0)" ::: "memory");
        s16x8 pfA, pfB;
        pfB = *(const s16x8*)&Plds[wslot][1][ml * 32 + ((quad ^ m3) * 8)];
        if (actA) pfA = *(const s16x8*)&Plds[wslot][0][ml * 32 + ((quad ^ m3) * 8)];
        asm volatile("s_waitcnt lgkmcnt(0)" ::: "memory");

        // PV + l (shared vf)
        if (actA) {
            #pragma unroll
            for (int nt = 0; nt < 8; ++nt) {
                s16x8 vf = *(const s16x8*)&vl[(nt * 16 + ml) * 32 + ((quad ^ m3) * 8)];
                OB[nt] = __builtin_amdgcn_mfma_f32_16x16x32_bf16(pfB, vf, OB[nt], 0, 0, 0);
                OA[nt] = __builtin_amdgcn_mfma_f32_16x16x32_bf16(pfA, vf, OA[nt], 0, 0, 0);
            }
            LB = __builtin_amdgcn_mfma_f32_16x16x32_bf16(pfB, ones, LB, 0, 0, 0);
            LA = __builtin_amdgcn_mfma_f32_16x16x32_bf16(pfA, ones, LA, 0, 0, 0);
        } else {
            #pragma unroll
            for (int nt = 0; nt < 8; ++nt) {
                s16x8 vf = *(const s16x8*)&vl[(nt * 16 + ml) * 32 + ((quad ^ m3) * 8)];
                OB[nt] = __builtin_amdgcn_mfma_f32_16x16x32_bf16(pfB, vf, OB[nt], 0, 0, 0);
            }
            LB = __builtin_amdgcn_mfma_f32_16x16x32_bf16(pfB, ones, LB, 0, 0, 0);
        }
    }

    #pragma unroll
    for (int nt = 0; nt < 8; ++nt)
        #pragma unroll
        for (int r = 0; r < 4; ++r) {
            int col = h * 128 + nt * 16 + ml;
            O[(size_t)(b * 2048 + t0b + quad * 4 + r) * 2048 + col] = f2bf(OB[nt][r] / LB[r]);
            O[(size_t)(b * 2048 + t0a + quad * 4 + r) * 2048 + col] = f2bf(OA[nt][r] / LA[r]);
        }
}

extern "C" void kernel_launch(void* const* d_in, const int* in_sizes, int n_in,
                              void* d_out, int out_size, void* d_ws, size_t ws_size,
                              hipStream_t stream) {
    const float* x  = (const float*)d_in[0];
    const float* wq = (const float*)d_in[1];
    const float* wk = (const float*)d_in[2];
    const float* wv = (const float*)d_in[3];
    const float* wo = (const float*)d_in[4];
    float* out = (float*)d_out;
    char* ws = (char*)d_ws;

    const size_t MB = 1024 * 1024;
    // ws (52MB): [0,16M) xb (reused as ab) | [16M,32M) qb | [32M,36M) kb |
    //            [36M,40M) vtb | [40M,52M) wqkvb (reused as wob after qkv GEMM)
    u16* xb    = (u16*)(ws);
    u16* qb    = (u16*)(ws + 16 * MB);
    u16* kb    = (u16*)(ws + 32 * MB);
    u16* vtb   = (u16*)(ws + 36 * MB);
    u16* wqkvb = (u16*)(ws + 40 * MB);
    u16* ab    = xb;    // attn output over xb (x last read by qkv GEMM)
    u16* wob   = wqkvb; // wo bf16 over wqkvb (last read by qkv GEMM)

    cvt_all<<<7168, 256, 0, stream>>>(x, wq, wk, wv, xb, wqkvb);

    gemm128<4><<<dim3(24, 32), 256, 0, stream>>>(xb, wqkvb, qb, kb, vtb, 4096, 3072, 2048);

    cvt_kernel<<<2048, 256, 0, stream>>>(wo, wob, 524288); // wqkvb region now free

    // q pre-scaled by 1/sqrt(128)*log2(e)
    rope_kernel<<<20480, 256, 0, stream>>>(qb, kb, 4194304, 5242880, 0.12751743f);

    attn_kernel<<<dim3(64, 8, 2), 128, 0, stream>>>(qb, kb, vtb, ab);

    gemm128<1><<<dim3(16, 32), 256, 0, stream>>>(ab, wob, out, nullptr, nullptr, 4096, 2048, 2048);
}

// Round 6
// 348.107 us; speedup vs baseline: 1.1432x; 1.1432x over previous
//
#include <hip/hip_runtime.h>

typedef float f32x4 __attribute__((ext_vector_type(4)));
typedef short s16x8 __attribute__((ext_vector_type(8)));
typedef unsigned short u16;

__device__ __forceinline__ u16 f2bf(float f) {
    union { float f; unsigned u; } v; v.f = f;
    return (u16)((v.u + 0x7fffu + ((v.u >> 16) & 1u)) >> 16);
}
__device__ __forceinline__ float bf2f(u16 h) {
    union { unsigned u; float f; } v; v.u = ((unsigned)h) << 16;
    return v.f;
}
__device__ __forceinline__ float fast_exp2(float x) {
#if __has_builtin(__builtin_amdgcn_exp2f)
    return __builtin_amdgcn_exp2f(x);
#else
    return exp2f(x);
#endif
}

// async global->LDS, 16B/lane; LDS dest = wave-uniform base + lane*16 [m97/m104]
__device__ __forceinline__ void gload_lds16(const void* g, void* l) {
    __builtin_amdgcn_global_load_lds((__attribute__((address_space(1))) void*)g,
                                     (__attribute__((address_space(3))) void*)l, 16, 0, 0);
}

// Mega convert: x (1048576 units) -> xb, then wq|wk|wv -> wqkvb contiguous. 1 unit = 8 elems.
__global__ __launch_bounds__(256) void cvt_all(const float* __restrict__ x,  const float* __restrict__ wq,
                                               const float* __restrict__ wk, const float* __restrict__ wv,
                                               u16* __restrict__ xb, u16* __restrict__ wqkvb) {
    int u = blockIdx.x * 256 + threadIdx.x;
    const float* src;
    u16* dst;
    if (u < 1048576) { src = x + (size_t)u * 8; dst = xb + (size_t)u * 8; }
    else {
        int w = u - 1048576;
        dst = wqkvb + (size_t)w * 8;
        if (w < 524288)      src = wq + (size_t)w * 8;
        else if (w < 655360) src = wk + (size_t)(w - 524288) * 8;
        else                 src = wv + (size_t)(w - 655360) * 8;
    }
    const float4* p = (const float4*)src;
    float4 a = p[0], b = p[1];
    s16x8 o;
    o[0] = f2bf(a.x); o[1] = f2bf(a.y); o[2] = f2bf(a.z); o[3] = f2bf(a.w);
    o[4] = f2bf(b.x); o[5] = f2bf(b.y); o[6] = f2bf(b.z); o[7] = f2bf(b.w);
    *(s16x8*)dst = o;
}

__global__ __launch_bounds__(256) void cvt_kernel(const float* __restrict__ in,
                                                  u16* __restrict__ out, int n8) {
    int i = blockIdx.x * 256 + threadIdx.x;
    if (i >= n8) return;
    const float4* p = (const float4*)(in + (size_t)i * 8);
    float4 a = p[0], b = p[1];
    s16x8 o;
    o[0] = f2bf(a.x); o[1] = f2bf(a.y); o[2] = f2bf(a.z); o[3] = f2bf(a.w);
    o[4] = f2bf(b.x); o[5] = f2bf(b.y); o[6] = f2bf(b.z); o[7] = f2bf(b.w);
    *(s16x8*)(out + (size_t)i * 8) = o;
}

// C = A[M,K] @ B[N,K]^T, bf16 in. 128x128 tile, BK=64, global_load_lds staging,
// XOR-swizzled LDS. OUT=1: fp32 C[M,N]. OUT=4: fused qkv routing.
template<int OUT>
__global__ __launch_bounds__(256) void gemm128(const u16* __restrict__ A, const u16* __restrict__ B,
                                               void* __restrict__ C, void* __restrict__ Ck,
                                               void* __restrict__ Cv, int M, int N, int K) {
    __shared__ __align__(16) u16 Ald[128 * 64];
    __shared__ __align__(16) u16 Bld[128 * 64];
    const int t = threadIdx.x, wid = t >> 6, lane = t & 63;
    const int m0 = blockIdx.y * 128, n0 = blockIdx.x * 128;
    const int ml = lane & 15, quad = lane >> 4, m7 = ml & 7;
    const int wm = (wid & 1) * 64, wn = (wid >> 1) * 64;
    const int sr = lane >> 3, sc = lane & 7;

    f32x4 acc[4][4] = {};

    for (int k0 = 0; k0 < K; k0 += 64) {
        if (k0) __syncthreads();
        #pragma unroll
        for (int i = 0; i < 4; ++i) {
            int seg = wid * 4 + i;
            int r = seg * 8 + sr;
            int c = (sc ^ (r & 7)) * 8;
            gload_lds16(A + (size_t)(m0 + r) * K + k0 + c, &Ald[seg * 512]);
            gload_lds16(B + (size_t)(n0 + r) * K + k0 + c, &Bld[seg * 512]);
        }
        __syncthreads();
        #pragma unroll
        for (int kk = 0; kk < 64; kk += 32) {
            s16x8 af[4], bf[4];
            #pragma unroll
            for (int mi = 0; mi < 4; ++mi)
                af[mi] = *(const s16x8*)&Ald[(wm + mi * 16 + ml) * 64 + (((kk >> 3) + quad) ^ m7) * 8];
            #pragma unroll
            for (int ni = 0; ni < 4; ++ni)
                bf[ni] = *(const s16x8*)&Bld[(wn + ni * 16 + ml) * 64 + (((kk >> 3) + quad) ^ m7) * 8];
            #pragma unroll
            for (int mi = 0; mi < 4; ++mi)
                #pragma unroll
                for (int ni = 0; ni < 4; ++ni)
                    acc[mi][ni] = __builtin_amdgcn_mfma_f32_16x16x32_bf16(af[mi], bf[ni], acc[mi][ni], 0, 0, 0);
        }
    }
    // C/D layout: col=lane&15, row=quad*4+reg [m89/m91]
    #pragma unroll
    for (int mi = 0; mi < 4; ++mi)
        #pragma unroll
        for (int ni = 0; ni < 4; ++ni) {
            int gmb = m0 + wm + mi * 16 + quad * 4;
            int gn  = n0 + wn + ni * 16 + ml;
            if constexpr (OUT == 4) {
                if (n0 < 2048) {
                    #pragma unroll
                    for (int r = 0; r < 4; ++r)
                        ((u16*)C)[(size_t)(gmb + r) * 2048 + gn] = f2bf(acc[mi][ni][r]);
                } else if (n0 < 2560) {
                    #pragma unroll
                    for (int r = 0; r < 4; ++r)
                        ((u16*)Ck)[(size_t)(gmb + r) * 512 + (gn - 2048)] = f2bf(acc[mi][ni][r]);
                } else {
                    ushort4 v;
                    v.x = f2bf(acc[mi][ni][0]); v.y = f2bf(acc[mi][ni][1]);
                    v.z = f2bf(acc[mi][ni][2]); v.w = f2bf(acc[mi][ni][3]);
                    *(ushort4*)((u16*)Cv + (size_t)(gn - 2560) * M + gmb) = v;
                }
            } else {
                #pragma unroll
                for (int r = 0; r < 4; ++r)
                    ((float*)C)[(size_t)(gmb + r) * N + gn] = acc[mi][ni][r];
            }
        }
}

// Fused NeoX RoPE for q (16 heads, scaled by 1/sqrt(128)*log2e) + k (4 heads).
__global__ __launch_bounds__(256) void rope_kernel(u16* __restrict__ qb, u16* __restrict__ kb,
                                                   int nq, int ntot, float sq) {
    int idx = blockIdx.x * 256 + threadIdx.x;
    if (idx >= ntot) return;
    u16* base; int nheads; float scl; int id;
    if (idx < nq) { base = qb; nheads = 16; scl = sq;  id = idx; }
    else          { base = kb; nheads = 4;  scl = 1.f; id = idx - nq; }
    int i = id & 63;
    int rest = id >> 6;
    int hh = rest % nheads;
    int tok = rest / nheads;
    int tpos = tok & 2047;
    u16* row = base + (size_t)tok * nheads * 128 + hh * 128;
    float x1 = bf2f(row[i]);
    float x2 = bf2f(row[i + 64]);
    float inv = expf(-(float)i * 0.14391156731570787f); // 10000^(-i/64)
    float ang = (float)tpos * inv;
    float s, c;
    sincosf(ang, &s, &c);
    row[i]      = f2bf((x1 * c - x2 * s) * scl);
    row[i + 64] = f2bf((x2 * c + x1 * s) * scl);
}

// Flash attention v4 = r4 skeleton + K double-buffer prefetch.
// Block = (pair, kv, b); 4 waves = 4 q-heads of the kv group; balanced q-tile pairs
// (qa, 127-qa); s-chunks of 64. Iter: barrier -> stage V[c] + prefetch K[c+1] ->
// QK on resident K[c] -> softmax/P-roundtrip (covers V flight) -> barrier (drain) -> PV.
// No exposed load latency. LDS = 2*16K (K) + 16K (V) + 16K (P) = 64KB exactly.
__global__ __launch_bounds__(256, 2) void attn_kernel(const u16* __restrict__ Q, const u16* __restrict__ Kb,
                                                      const u16* __restrict__ Vt, u16* __restrict__ O) {
    __shared__ __align__(16) u16 Klds[2][64 * 128];    // 16KB x2 (double-buffered)
    __shared__ __align__(16) u16 Vlds[128 * 64];       // 16KB
    __shared__ __align__(16) u16 Plds[4][2][16 * 64];  // 16KB (2 tiles per wave)
    const int t = threadIdx.x, wslot = t >> 6, lane = t & 63;
    const int qa = blockIdx.x, qbt = 127 - (int)blockIdx.x;
    const int kv = blockIdx.y, b = blockIdx.z;
    const int h = kv * 4 + wslot;
    const int ml = lane & 15, quad = lane >> 4, m7 = ml & 7;
    const int t0a = qa * 16, t0b = qbt * 16;

    // Q fragments: A layout m=lane&15, k=quad*8+j [m120]
    s16x8 qfA[4], qfB[4];
    {
        const u16* qpA = Q + ((size_t)(b * 2048 + t0a + ml) * 2048 + h * 128);
        const u16* qpB = Q + ((size_t)(b * 2048 + t0b + ml) * 2048 + h * 128);
        #pragma unroll
        for (int kc = 0; kc < 4; ++kc) {
            qfA[kc] = *(const s16x8*)(qpA + kc * 32 + quad * 8);
            qfB[kc] = *(const s16x8*)(qpB + kc * 32 + quad * 8);
        }
    }

    s16x8 ones;
    #pragma unroll
    for (int j = 0; j < 8; ++j) ones[j] = (short)0x3F80; // bf16 1.0

    f32x4 OA[8] = {}, OB[8] = {};
    f32x4 LA = {}, LB = {};

    const int nsb = (qbt >> 2) + 1;
    const int lastA = qa >> 2;

    // K-stage s-chunk c into buffer bi (per wave 4 segs of 4 rows x 256B, swizzled)
    auto stageK = [&](int bi, int c) {
        const int s0 = c * 64;
        #pragma unroll
        for (int i = 0; i < 4; ++i) {
            int seg = wslot * 4 + i;
            int kr = seg * 4 + (lane >> 4);
            int kc = ((lane & 15) ^ (kr & 7)) * 8;
            gload_lds16(Kb + (size_t)(b * 2048 + s0 + kr) * 512 + kv * 128 + kc, &Klds[bi][seg * 512]);
        }
    };
    // V-stage s-chunk c (per wave 4 segs of 8 rows x 128B, swizzled)
    auto stageV = [&](int c) {
        const int s0 = c * 64;
        #pragma unroll
        for (int i = 0; i < 4; ++i) {
            int seg = wslot * 4 + i;
            int vr = seg * 8 + (lane >> 3);
            int vc = ((lane & 7) ^ (vr & 7)) * 8;
            gload_lds16(Vt + (size_t)(kv * 128 + vr) * 4096 + b * 2048 + s0 + vc, &Vlds[seg * 512]);
        }
    };

    stageK(0, 0);

    for (int it = 0; it < nsb; ++it) {
        const int s0 = it * 64;
        // barrier1: own vmcnt drain completes K[it] (issued last iter) and V[it-1];
        // all waves past PV of it-1, so Vlds free and Klds[it&1] fully staged.
        __syncthreads();
        stageV(it);
        if (it + 1 < nsb) stageK((it + 1) & 1, it + 1);

        const u16* kl = Klds[it & 1];
        const bool actA = (it <= lastA);

        // QK^T on resident K tile (shared kf: each feeds both pair tiles)
        f32x4 Sa[4] = {}, Sb[4] = {};
        if (actA) {
            #pragma unroll
            for (int kc = 0; kc < 4; ++kc)
                #pragma unroll
                for (int ti = 0; ti < 4; ++ti) {
                    s16x8 kf = *(const s16x8*)&kl[(ti * 16 + ml) * 128 + ((kc * 4 + quad) ^ m7) * 8];
                    Sb[ti] = __builtin_amdgcn_mfma_f32_16x16x32_bf16(qfB[kc], kf, Sb[ti], 0, 0, 0);
                    Sa[ti] = __builtin_amdgcn_mfma_f32_16x16x32_bf16(qfA[kc], kf, Sa[ti], 0, 0, 0);
                }
        } else {
            #pragma unroll
            for (int kc = 0; kc < 4; ++kc)
                #pragma unroll
                for (int ti = 0; ti < 4; ++ti) {
                    s16x8 kf = *(const s16x8*)&kl[(ti * 16 + ml) * 128 + ((kc * 4 + quad) ^ m7) * 8];
                    Sb[ti] = __builtin_amdgcn_mfma_f32_16x16x32_bf16(qfB[kc], kf, Sb[ti], 0, 0, 0);
                }
        }

        // softmax (no max-shift, log2 domain): p = exp2(s); causal mask -> 0
        auto do_soft = [&](f32x4* S, int t0, int pslot) {
            u16* pl = &Plds[wslot][pslot][0];
            #pragma unroll
            for (int r = 0; r < 4; ++r) {
                int qr = t0 + quad * 4 + r;
                int row = quad * 4 + r;
                #pragma unroll
                for (int ti = 0; ti < 4; ++ti) {
                    float e = fast_exp2(S[ti][r]);
                    if (s0 + ti * 16 + ml > qr) e = 0.f;
                    union { float f; unsigned u; } cv; cv.f = e;
                    pl[row * 64 + (((ti * 2 + (ml >> 3)) ^ (row & 7)) * 8) + (ml & 7)] = (u16)(cv.u >> 16);
                }
            }
        };
        do_soft(Sb, t0b, 1);
        if (actA) do_soft(Sa, t0a, 0);
        asm volatile("s_waitcnt lgkmcnt(0)" ::: "memory");
        s16x8 pfA[2], pfB[2];
        pfB[0] = *(const s16x8*)&Plds[wslot][1][ml * 64 + ((quad)     ^ m7) * 8];
        pfB[1] = *(const s16x8*)&Plds[wslot][1][ml * 64 + ((4 + quad) ^ m7) * 8];
        if (actA) {
            pfA[0] = *(const s16x8*)&Plds[wslot][0][ml * 64 + ((quad)     ^ m7) * 8];
            pfA[1] = *(const s16x8*)&Plds[wslot][0][ml * 64 + ((4 + quad) ^ m7) * 8];
        }
        asm volatile("s_waitcnt lgkmcnt(0)" ::: "memory");

        // barrier2: drains own vmcnt -> V[it] complete across all waves (V flight was
        // covered by QK+softmax; K[it+1] also drains but had QK+softmax of slack).
        __syncthreads();

        // PV + l (shared vf)
        if (actA) {
            #pragma unroll
            for (int c = 0; c < 2; ++c) {
                #pragma unroll
                for (int nt = 0; nt < 8; ++nt) {
                    s16x8 vf = *(const s16x8*)&Vlds[(nt * 16 + ml) * 64 + ((c * 4 + quad) ^ m7) * 8];
                    OB[nt] = __builtin_amdgcn_mfma_f32_16x16x32_bf16(pfB[c], vf, OB[nt], 0, 0, 0);
                    OA[nt] = __builtin_amdgcn_mfma_f32_16x16x32_bf16(pfA[c], vf, OA[nt], 0, 0, 0);
                }
                LB = __builtin_amdgcn_mfma_f32_16x16x32_bf16(pfB[c], ones, LB, 0, 0, 0);
                LA = __builtin_amdgcn_mfma_f32_16x16x32_bf16(pfA[c], ones, LA, 0, 0, 0);
            }
        } else {
            #pragma unroll
            for (int c = 0; c < 2; ++c) {
                #pragma unroll
                for (int nt = 0; nt < 8; ++nt) {
                    s16x8 vf = *(const s16x8*)&Vlds[(nt * 16 + ml) * 64 + ((c * 4 + quad) ^ m7) * 8];
                    OB[nt] = __builtin_amdgcn_mfma_f32_16x16x32_bf16(pfB[c], vf, OB[nt], 0, 0, 0);
                }
                LB = __builtin_amdgcn_mfma_f32_16x16x32_bf16(pfB[c], ones, LB, 0, 0, 0);
            }
        }
    }

    #pragma unroll
    for (int nt = 0; nt < 8; ++nt)
        #pragma unroll
        for (int r = 0; r < 4; ++r) {
            int col = h * 128 + nt * 16 + ml;
            O[(size_t)(b * 2048 + t0b + quad * 4 + r) * 2048 + col] = f2bf(OB[nt][r] / LB[r]);
            O[(size_t)(b * 2048 + t0a + quad * 4 + r) * 2048 + col] = f2bf(OA[nt][r] / LA[r]);
        }
}

extern "C" void kernel_launch(void* const* d_in, const int* in_sizes, int n_in,
                              void* d_out, int out_size, void* d_ws, size_t ws_size,
                              hipStream_t stream) {
    const float* x  = (const float*)d_in[0];
    const float* wq = (const float*)d_in[1];
    const float* wk = (const float*)d_in[2];
    const float* wv = (const float*)d_in[3];
    const float* wo = (const float*)d_in[4];
    float* out = (float*)d_out;
    char* ws = (char*)d_ws;

    const size_t MB = 1024 * 1024;
    // ws (52MB): [0,16M) xb (reused as ab) | [16M,32M) qb | [32M,36M) kb |
    //            [36M,40M) vtb | [40M,52M) wqkvb (reused as wob after qkv GEMM)
    u16* xb    = (u16*)(ws);
    u16* qb    = (u16*)(ws + 16 * MB);
    u16* kb    = (u16*)(ws + 32 * MB);
    u16* vtb   = (u16*)(ws + 36 * MB);
    u16* wqkvb = (u16*)(ws + 40 * MB);
    u16* ab    = xb;    // attn output over xb (x last read by qkv GEMM)
    u16* wob   = wqkvb; // wo bf16 over wqkvb (last read by qkv GEMM)

    cvt_all<<<7168, 256, 0, stream>>>(x, wq, wk, wv, xb, wqkvb);

    gemm128<4><<<dim3(24, 32), 256, 0, stream>>>(xb, wqkvb, qb, kb, vtb, 4096, 3072, 2048);

    cvt_kernel<<<2048, 256, 0, stream>>>(wo, wob, 524288); // wqkvb region now free

    // q pre-scaled by 1/sqrt(128)*log2(e)
    rope_kernel<<<20480, 256, 0, stream>>>(qb, kb, 4194304, 5242880, 0.12751743f);

    attn_kernel<<<dim3(64, 4, 2), 256, 0, stream>>>(qb, kb, vtb, ab);

    gemm128<1><<<dim3(16, 32), 256, 0, stream>>>(ab, wob, out, nullptr, nullptr, 4096, 2048, 2048);
}